// Round 1
// baseline (1077.504 us; speedup 1.0000x reference)
//
#include <hip/hip_runtime.h>
#include <math.h>

// BilateralNet: 12 conv variants (3 modes x 4 rotations, rotations folded into
// tap-coordinate maps) -> fused per-pixel MLP (64->128->192->256->320->4) in LDS
// -> averaged par map -> 5x5 adaptive bilateral filter.
//
// Layout decisions:
//  - par accumulator lives in d_out[51200..256000) (ch-major [ch][b][pix]);
//    kernel2 reads its own 4 slots and overwrites them with sigx/sigy/theta/sigr
//    (exactly the expected output layout; no cross-thread hazard).
//  - activations X[320][64] bf16 in LDS (40 KB -> 4 blocks/CU).
//  - weights fp32 from global via wave-uniform scalar loads (og = wave id).

#define NN   160
#define NPIX 25600   // 160*160

__device__ __forceinline__ int refp(int a) { return (a <= NN - 1) ? a : (2 * (NN - 1) - a); }

__device__ __forceinline__ unsigned short f2b(float f) {
    unsigned int x = __float_as_uint(f);
    return (unsigned short)((x + 0x7FFFu + ((x >> 16) & 1u)) >> 16);  // RNE bf16
}
__device__ __forceinline__ float b2f(unsigned short u) {
    return __uint_as_float(((unsigned int)u) << 16);
}

template <int K>
__device__ __forceinline__ void dense_layer(const float* __restrict__ Wg,
                                            const float* __restrict__ Bg,
                                            int ogu, int p,
                                            unsigned short (*X)[64]) {
    // computes F[o][p] = relu(sum_i W[o][i] * X[i][p] + B[o]) for o in [ogu*16, ogu*16+16)
    // writes into X[K .. K+64). Reads [0,K) / writes [K,K+64) are disjoint -> no sync inside.
    float acc[16];
#pragma unroll
    for (int oo = 0; oo < 16; ++oo) acc[oo] = Bg[ogu * 16 + oo];
    const float* W0 = Wg + ogu * 16 * K;  // wave-uniform base -> scalar loads
#pragma unroll 4
    for (int i = 0; i < K; ++i) {
        float xv = b2f(X[i][p]);
#pragma unroll
        for (int oo = 0; oo < 16; ++oo)
            acc[oo] = fmaf(W0[oo * K + i], xv, acc[oo]);
    }
#pragma unroll
    for (int oo = 0; oo < 16; ++oo)
        X[K + ogu * 16 + oo][p] = f2b(fmaxf(acc[oo], 0.0f));
}

__global__ __launch_bounds__(256) void bnet_mlp_kernel(
    const float* __restrict__ x,
    const float* __restrict__ wx, const float* __restrict__ bx,
    const float* __restrict__ wcs, const float* __restrict__ bcs,
    const float* __restrict__ wc, const float* __restrict__ bc,
    const float* __restrict__ w2, const float* __restrict__ b2,
    const float* __restrict__ w3, const float* __restrict__ b3,
    const float* __restrict__ w4, const float* __restrict__ b4,
    const float* __restrict__ w5, const float* __restrict__ b5,
    const float* __restrict__ w6, const float* __restrict__ b6,
    float* __restrict__ par)  // par[ch][b][pix], ch-major; pre-zeroed
{
    __shared__ unsigned short X[320][64];  // bf16 activations, 40 KB

    const int t = threadIdx.x;
    const int p = t & 63;
    const int ogu = __builtin_amdgcn_readfirstlane(t >> 6);  // wave id 0..3, wave-uniform

    const int bid = blockIdx.x;          // 2400 blocks = 400 tiles * 2 batches * 3 modes
    const int tile = bid % 400;
    const int b = (bid / 400) & 1;
    const int mode = bid / 800;          // 0='x', 1='s', 2='c'

    const int pix = tile * 64 + p;
    const int pi = pix / NN;
    const int pj = pix - pi * NN;
    const float* xb = x + b * NPIX;

    // mode-specific stage-1 weights and tap offsets
    const float* w1 = (mode == 0) ? wx : (mode == 1) ? wcs : wc;
    const float* b1 = (mode == 0) ? bx : (mode == 1) ? bcs : bc;
    int DY[4], DX[4];
    if (mode == 0) { DY[0]=0; DY[1]=0; DY[2]=1; DY[3]=1;  DX[0]=0; DX[1]=1; DX[2]=0; DX[3]=1; }
    else if (mode == 1) { DY[0]=0; DY[1]=1; DY[2]=1; DY[3]=2;  DX[0]=0; DX[1]=1; DX[2]=2; DX[3]=1; }
    else { DY[0]=0; DY[1]=0; DY[2]=2; DY[3]=2;  DX[0]=0; DX[1]=2; DX[2]=0; DX[3]=2; }

    float par_reg = 0.0f;  // this thread accumulates par channel ch=ogu for pixel p

    for (int k = 0; k < 4; ++k) {
        __syncthreads();  // protect X[0..64) writes vs previous iteration's final-layer reads

        // ---- stage 1: 4-tap conv with rotation folded into tap coordinates ----
        float s[4];
#pragma unroll
        for (int tt = 0; tt < 4; ++tt) {
            const int dy = DY[tt], dx = DX[tt];
            int r, c;
            if (k == 0)      { r = refp(pi + dy); c = refp(pj + dx); }
            else if (k == 1) { r = refp(pi + dx); c = (pj >= dy) ? (pj - dy) : (dy - pj); }
            else if (k == 2) { r = (pi >= dy) ? (pi - dy) : (dy - pi);
                               c = (pj >= dx) ? (pj - dx) : (dx - pj); }
            else             { r = (pi >= dx) ? (pi - dx) : (dx - pi); c = refp(pj + dy); }
            s[tt] = xb[r * NN + c];
        }
#pragma unroll
        for (int oo = 0; oo < 16; ++oo) {
            const int o = ogu * 16 + oo;
            float cacc = b1[o];
#pragma unroll
            for (int tt = 0; tt < 4; ++tt) cacc = fmaf(w1[o * 4 + tt], s[tt], cacc);
            X[o][p] = f2b(fmaxf(cacc, 0.0f));
        }
        __syncthreads();

        dense_layer<64>(w2, b2, ogu, p, X);
        __syncthreads();
        dense_layer<128>(w3, b3, ogu, p, X);
        __syncthreads();
        dense_layer<192>(w4, b4, ogu, p, X);
        __syncthreads();
        dense_layer<256>(w5, b5, ogu, p, X);
        __syncthreads();

        // ---- final layer: 4 outputs; wave og computes channel ch=og ----
        float acc = b6[ogu];
#pragma unroll 8
        for (int i = 0; i < 320; ++i)
            acc = fmaf(w6[ogu * 320 + i], b2f(X[i][p]), acc);
        par_reg += acc;
    }

    atomicAdd(&par[(ogu * 2 + b) * NPIX + pix], par_reg);
}

__global__ __launch_bounds__(256) void bnet_bilateral_kernel(
    const float* __restrict__ x, float* __restrict__ out)
{
    const int tid = blockIdx.x * 256 + threadIdx.x;  // 51200 threads exactly
    const int b = tid / NPIX;
    const int pix = tid - b * NPIX;
    const int pi = pix / NN;
    const int pj = pix - pi * NN;

    float* par = out + 2 * NPIX;  // 51200
    const float inv12 = 1.0f / 12.0f;
    const float p0 = par[(0 + b) * NPIX + pix] * inv12;
    const float p1 = par[(2 + b) * NPIX + pix] * inv12;
    const float p2 = par[(4 + b) * NPIX + pix] * inv12;
    const float p3 = par[(6 + b) * NPIX + pix] * inv12;

    float sigx = 1.0f / (1.0f + expf(-p0)) + 1e-6f;
    sigx = fminf(fmaxf(sigx, 0.0f), 1.0f);
    float sigy = 1.0f / (1.0f + expf(-p1)) + 1e-6f;
    sigy = fminf(fmaxf(sigy, 0.0f), 1.0f);
    float th = tanhf(p2);
    th = fminf(fmaxf(th, -1.0f), 1.0f);
    float sigr = tanhf(p3) + 1e-6f;
    sigr = fminf(fmaxf(sigr, -1.0f), 1.0f);

    // write the 4 sigma outputs over this thread's own par slots (layout matches output)
    par[(0 + b) * NPIX + pix] = sigx;
    par[(2 + b) * NPIX + pix] = sigy;
    par[(4 + b) * NPIX + pix] = th;
    par[(6 + b) * NPIX + pix] = sigr;

    const float sx = sigx * 20.0f;
    const float sy = sigy * 20.0f;
    const float sr = sigr * 10.0f + 10.0f;

    const float* xb = x + b * NPIX;
    float patch[5][5];
#pragma unroll
    for (int ky = 0; ky < 5; ++ky) {
#pragma unroll
        for (int kx = 0; kx < 5; ++kx) {
            const int r = pi + ky - 2, c = pj + kx - 2;
            patch[ky][kx] = (r >= 0 && r < NN && c >= 0 && c < NN) ? xb[r * NN + c] : 0.0f;
        }
    }

    const float inv2sr2 = 1.0f / (2.0f * sr * sr);
    float num = 0.0f, den = 0.0f;
#pragma unroll
    for (int ky = 0; ky < 5; ++ky) {
#pragma unroll
        for (int kx = 0; kx < 5; ++kx) {
            const float v = patch[ky][kx];
            const float dxv = fabsf(patch[2][kx] - v);
            const float dyv = fabsf(patch[ky][2] - v);
            const float a = sx * dxv;
            const float bb = sy * dyv;
            const float sq = (float)((ky - 2) * (ky - 2) + (kx - 2) * (kx - 2));
            const float kern = expf(-sq * inv2sr2 - 0.5f * (a * a - 2.0f * th * a * bb + bb * bb));
            den += kern;
            num = fmaf(kern, v, num);
        }
    }
    out[tid] = num / den;  // outs is (b,1,H,W) flat = tid
}

extern "C" void kernel_launch(void* const* d_in, const int* in_sizes, int n_in,
                              void* d_out, int out_size, void* d_ws, size_t ws_size,
                              hipStream_t stream) {
    const float* x   = (const float*)d_in[0];
    const float* wx  = (const float*)d_in[1];
    const float* bx  = (const float*)d_in[2];
    const float* wc  = (const float*)d_in[3];
    const float* bc  = (const float*)d_in[4];
    const float* wcs = (const float*)d_in[5];
    const float* bcs = (const float*)d_in[6];
    const float* w2  = (const float*)d_in[7];
    const float* b2  = (const float*)d_in[8];
    const float* w3  = (const float*)d_in[9];
    const float* b3  = (const float*)d_in[10];
    const float* w4  = (const float*)d_in[11];
    const float* b4  = (const float*)d_in[12];
    const float* w5  = (const float*)d_in[13];
    const float* b5  = (const float*)d_in[14];
    const float* w6  = (const float*)d_in[15];
    const float* b6  = (const float*)d_in[16];
    float* out = (float*)d_out;

    // zero the par accumulator region (d_out tail, re-poisoned each launch)
    hipMemsetAsync(out + 2 * NPIX, 0, 8 * NPIX * sizeof(float), stream);

    hipLaunchKernelGGL(bnet_mlp_kernel, dim3(2400), dim3(256), 0, stream,
                       x, wx, bx, wcs, bcs, wc, bc,
                       w2, b2, w3, b3, w4, b4, w5, b5, w6, b6,
                       out + 2 * NPIX);

    hipLaunchKernelGGL(bnet_bilateral_kernel, dim3(200), dim3(256), 0, stream,
                       x, out);
}